// Round 15
// baseline (128.149 us; speedup 1.0000x reference)
//
#include <hip/hip_runtime.h>
#include <hip/hip_bf16.h>
#include <hip/hip_fp8.h>

// ContrastiveLoss (SimCLR InfoNCE): N=8192, D=1024, T=0.1
// nll[i] = -logit[i, (i+N/2)%N] + logsumexp_j(logit[i,j]), diag masked out
// logit = cos_sim / T; out = mean(nll)
//
// Identities:
//  - zn_i = z_i * sqrt(10*log2e)/||z_i||  =>  dot d = logit*log2e and
//    exp(logit-10) = 2^(d - 10*log2e) -> raw v_exp_f32.
//  - logit in [-10,10] => FIXED-offset logsumexp; masked diag term == 0.
//  - Gram symmetric: upper-tri 128x128 supertiles (2080); off-diag tile
//    (I,J) adds exp row-sums to rows of I, col-sums to rows of J.
//  - positive-pair logits = tile diagonals of supertiles (I, I+32).
//  - MX-scaled fp8 K=128 MFMA with all scales = 1.0 (2x bf16 rate).
//
// R27 = R25 reverted (session best: gemm 52.9us, total 121.4us). R26's
// split-MFMA regressed to 62.6us: the 8 MFMAs placed between frag reads
// and barrier2 extended every wave's pre-barrier critical path, delaying
// the block-wide staging issue -- everything between entry barrier and
// barrier2 is serial block-wide cost, and R25 already minimizes it.
// R25's structure: counted-vmcnt at 3 blocks/CU (the regime where it's
// real -- null at 2 blk, rule #23). Phase: entry vmcnt(4)+barrier (B(p),
// A(p) issued >=1 full phase ago -> wait ~free; newest 4 = A(p+2) stay in
// flight; only p=7 drains) -> hoist BOTH frag sets -> lgkm(0)+barrier2 ->
// stage B(p+1) + A(p+2) (A two-deep into the buffer just read) -> 16 MFMA
// under setprio. Supercell L2 ordering (FETCH 66->23MB), global-side XOR
// swizzle, 50KB LDS, ~164 regs <= 170 at (256,3), VGPR 84 / WRITE 18.6MB
// verified clean. Box probed on every axis over 15 rounds; two real
// levers found (L2 ordering -14%, counted-vmcnt@3blk -6%); remaining gap
// is barrier-convoy latency structural to this geometry.

#define N_ROWS 8192
#define DIM    1024
#define BM 128
#define BK 128                         // bytes (= elems) of K per phase
#define NPHASE (DIM / BK)              // 8
#define NT     (N_ROWS / BM)           // 64
#define NTILES (NT * (NT + 1) / 2)     // 2080
#define OFFS   14.4269504088896340f    // 10 * log2e
#define ROW_SCALE 3.7982825605f        // sqrt(10 * log2e)
#define LN2    0.6931471805599453f
#define LOGIT_MAX 10.0f
#define SCALE1 0x7F7F7F7F              // e8m0 1.0 in every byte

typedef float floatx4 __attribute__((ext_vector_type(4)));
typedef int   intx4   __attribute__((ext_vector_type(4)));
typedef int   intx8   __attribute__((ext_vector_type(8)));

__device__ __forceinline__ void async_copy16(const void* g, void* lds) {
  __builtin_amdgcn_global_load_lds(
      (const __attribute__((address_space(1))) void*)g,
      (__attribute__((address_space(3))) void*)lds, 16, 0, 0);
}

__device__ __forceinline__ unsigned pack4_e4m3(float a, float b, float c, float d) {
  __hip_fp8_e4m3 qa(a), qb(b), qc(c), qd(d);
  return (unsigned)qa.__x | ((unsigned)qb.__x << 8) |
         ((unsigned)qc.__x << 16) | ((unsigned)qd.__x << 24);
}

// ---------------- Kernel 1: row normalize -> fp8 (+ zero accumulators) ----
__global__ __launch_bounds__(256) void normalize_kernel(
    const float* __restrict__ z, unsigned char* __restrict__ zn,
    float* __restrict__ sumexp, float* __restrict__ out) {
  const int tid = threadIdx.x, wave = tid >> 6, lane = tid & 63;
  const int row = blockIdx.x * 4 + wave;

  if (blockIdx.x < 8) ((float4*)sumexp)[blockIdx.x * 256 + tid] = float4{0, 0, 0, 0};
  if (blockIdx.x == 8 && tid == 0) out[0] = 0.0f;

  const float4* zr = (const float4*)(z + (size_t)row * DIM);
  float4 v[4];
  #pragma unroll
  for (int j = 0; j < 4; j++) v[j] = zr[lane + 64 * j];
  float ss = 0.0f;
  #pragma unroll
  for (int j = 0; j < 4; j++)
    ss += v[j].x * v[j].x + v[j].y * v[j].y + v[j].z * v[j].z + v[j].w * v[j].w;
  #pragma unroll
  for (int off = 32; off > 0; off >>= 1) ss += __shfl_xor(ss, off);
  const float scale = rsqrtf(ss) * ROW_SCALE;  // norms ~32 >> eps

  unsigned* o = (unsigned*)(zn + (size_t)row * DIM);
  #pragma unroll
  for (int j = 0; j < 4; j++)
    o[lane + 64 * j] = pack4_e4m3(v[j].x * scale, v[j].y * scale,
                                  v[j].z * scale, v[j].w * scale);
}

// Supercell-major tile decode: 64x64 upper-tri grid partitioned into 8x8
// supercells (rows SI, cols SJ >= SI). Diag cell = 36 tiles, off-diag = 64.
// Prefix P(SI) = 516*SI - 32*SI*SI (P(8)=2080). Within a cell-row: diag
// cell first, then snake over off-diag cells; within cell row-major.
// Confirmed R17: FETCH 66->23MB, gemm 65.3->56.4us.
__device__ __forceinline__ void decode_tile(int g, int& I, int& J) {
  int SI = 0;
  #pragma unroll
  for (int s = 1; s < 8; ++s)
    if (516 * s - 32 * s * s <= g) SI = s;
  int rem = g - (516 * SI - 32 * SI * SI);
  int i, j, SJ;
  if (rem < 36) {                       // diagonal supercell, upper-tri 8x8
    SJ = SI;
    i = 0;
    while ((i + 1) * (17 - (i + 1)) / 2 <= rem) ++i;  // prefix(i)=i*(17-i)/2
    j = i + (rem - i * (17 - i) / 2);
  } else {                              // full off-diagonal supercell
    const int rem2 = rem - 36;
    const int cc = rem2 >> 6;           // 0 .. (6-SI)
    const int k  = rem2 & 63;
    SJ = (SI & 1) ? (7 - cc) : (SI + 1 + cc);
    i = k >> 3;
    j = k & 7;
  }
  I = SI * 8 + i;
  J = SJ * 8 + j;
}

// ---------------- Kernel 2: upper-tri MX-fp8 GEMM + partial sum-exp -------
__global__ __launch_bounds__(256, 3) void fused_gemm_lse(
    const unsigned char* __restrict__ zn, float* __restrict__ sumexp,
    float* __restrict__ pos) {
  __shared__ unsigned char sA[2][BM * BK];    // 2 x 16 KB (2-deep DMA dbuf)
  __shared__ unsigned char sB[BM * BK];       // 16 KB (single, 1-deep)
  __shared__ float rowRed[2][BM];             // 1 KB
  __shared__ float colRed[2][BM];             // 1 KB   (total 50 KB)

  const int tid  = threadIdx.x;
  const int lane = tid & 63;
  const int wave = tid >> 6;
  const int quad = lane >> 4;
  const int l15  = lane & 15;
  const int waveM = wave >> 1;  // 0..1
  const int waveN = wave & 1;   // 0..1

  // XCD-contiguous tile permutation (2080 = 8 * 260)
  const int t = (blockIdx.x & 7) * (NTILES / 8) + (blockIdx.x >> 3);
  int I, J;
  decode_tile(t, I, J);
  const int rowBase = I * BM, colBase = J * BM;

  // staging: 128x128B tile = 1024 16B-chunks, 4/thread/matrix.
  // chunk s = i*256+tid: row r = s>>3, stored slot s&7 holds logical
  // k-chunk q = (s&7)^(r&7) (XOR swizzle on the global-address side).
  // LDS dest is linear: s*16 = i*4096 + tid*16.
  int rOff[4];
  #pragma unroll
  for (int i = 0; i < 4; i++) {
    const int s = i * 256 + tid;
    const int r = s >> 3;
    const int q = (s & 7) ^ (r & 7);
    rOff[i] = r * DIM + q * 16;
  }
  const unsigned char* gA = zn + (size_t)rowBase * DIM;
  const unsigned char* gB = zn + (size_t)colBase * DIM;
  const int ldsOff = tid * 16;

  auto stageA = [&](int buf, int p) {
    const unsigned char* g = gA + p * BK;
    #pragma unroll
    for (int i = 0; i < 4; i++)
      async_copy16(g + rOff[i], (char*)sA[buf] + i * 4096 + ldsOff);
  };
  auto stageB = [&](int p) {
    const unsigned char* g = gB + p * BK;
    #pragma unroll
    for (int i = 0; i < 4; i++)
      async_copy16(g + rOff[i], (char*)sB + i * 4096 + ldsOff);
  };

  floatx4 acc[4][4];
  #pragma unroll
  for (int mi = 0; mi < 4; mi++)
    #pragma unroll
    for (int ni = 0; ni < 4; ni++) acc[mi][ni] = {0.f, 0.f, 0.f, 0.f};

  // prologue: B(0), A(0), A(1) in flight (12 insts); entry p=0 waits
  // vmcnt(4) -> drains B(0),A(0), leaves A(1) flying (steady invariant).
  stageB(0);
  stageA(0, 0);
  stageA(1, 1);

  for (int p = 0; p < NPHASE; ++p) {
    const int b = p & 1;
    // entry: B(p),A(p) resident (issued >= 1 full phase ago -> wait ~free);
    // newest 4 outstanding = A(p+2)'s predecessor set; only p=7 drains all.
    if (p < NPHASE - 1) asm volatile("s_waitcnt vmcnt(4)" ::: "memory");
    else                asm volatile("s_waitcnt vmcnt(0)" ::: "memory");
    __builtin_amdgcn_s_barrier();

    // hoist BOTH operand fragment sets (barrier2 then covers all reads)
    intx8 aa[4], bb[4];
    #pragma unroll
    for (int ni = 0; ni < 4; ni++) {
      const int r = waveN * 64 + ni * 16 + l15;
      const int c0 = (quad * 2) ^ (r & 7);
      const intx4 lo = *(const intx4*)(&sB[0] + (r * 8 + c0) * 16);
      const intx4 hi = *(const intx4*)(&sB[0] + (r * 8 + (c0 ^ 1)) * 16);
      bb[ni] = __builtin_shufflevector(lo, hi, 0, 1, 2, 3, 4, 5, 6, 7);
    }
    #pragma unroll
    for (int mi = 0; mi < 4; mi++) {
      const int r = waveM * 64 + mi * 16 + l15;
      const int c0 = (quad * 2) ^ (r & 7);
      const intx4 lo = *(const intx4*)(&sA[b][0] + (r * 8 + c0) * 16);
      const intx4 hi = *(const intx4*)(&sA[b][0] + (r * 8 + (c0 ^ 1)) * 16);
      aa[mi] = __builtin_shufflevector(lo, hi, 0, 1, 2, 3, 4, 5, 6, 7);
    }
    asm volatile("s_waitcnt lgkmcnt(0)" ::: "memory");
    __builtin_amdgcn_sched_barrier(0);
    __builtin_amdgcn_s_barrier();        // all waves done with sB and sA[b]

    // stage: B(p+1) -> sB (freed), A(p+2) -> sA[b] (freed). Issue order
    // B-then-A keeps the entry vmcnt(4) invariant (newest 4 = A batch).
    if (p + 1 < NPHASE) stageB(p + 1);
    if (p + 2 < NPHASE) stageA(b, p + 2);

    __builtin_amdgcn_s_setprio(1);
    #pragma unroll
    for (int mi = 0; mi < 4; mi++)
      #pragma unroll
      for (int ni = 0; ni < 4; ni++)
        acc[mi][ni] = __builtin_amdgcn_mfma_scale_f32_16x16x128_f8f6f4(
            aa[mi], bb[ni], acc[mi][ni],
            0 /*cbsz: A=e4m3*/, 0 /*blgp: B=e4m3*/,
            0, SCALE1,   // opsel_a, scale_a = 1.0
            0, SCALE1);  // opsel_b, scale_b = 1.0
    __builtin_amdgcn_s_setprio(0);
  }

  // ---- epilogue ----
  // C/D layout (16x16 shape family): col = lane&15, row = quad*4 + reg
  const bool diagBlk = (I == J);

  if (J == I + 32 && waveM == waveN) {  // positive-pair supertile
    #pragma unroll
    for (int mi = 0; mi < 4; mi++)
      #pragma unroll
      for (int r = 0; r < 4; r++)
        if (l15 == quad * 4 + r)
          pos[rowBase + waveM * 64 + mi * 16 + l15] = acc[mi][mi][r];
  }

  float rsum[4][4], csum[4];
  #pragma unroll
  for (int mi = 0; mi < 4; mi++)
    #pragma unroll
    for (int r = 0; r < 4; r++) rsum[mi][r] = 0.0f;
  #pragma unroll
  for (int ni = 0; ni < 4; ni++) csum[ni] = 0.0f;

  if (diagBlk) {
    #pragma unroll
    for (int mi = 0; mi < 4; mi++)
      #pragma unroll
      for (int ni = 0; ni < 4; ni++) {
        const bool dtile = (waveM == waveN) && (mi == ni);
        #pragma unroll
        for (int r = 0; r < 4; r++) {
          float e = exp2f(acc[mi][ni][r] - OFFS);
          if (dtile && l15 == quad * 4 + r) e = 0.0f;  // masked diagonal
          rsum[mi][r] += e;
        }
      }
  } else {
    #pragma unroll
    for (int mi = 0; mi < 4; mi++)
      #pragma unroll
      for (int ni = 0; ni < 4; ni++)
        #pragma unroll
        for (int r = 0; r < 4; r++) {
          const float e = exp2f(acc[mi][ni][r] - OFFS);
          rsum[mi][r] += e;
          csum[ni]    += e;
        }
  }

  #pragma unroll
  for (int mi = 0; mi < 4; mi++)
    #pragma unroll
    for (int r = 0; r < 4; r++) {
      float v = rsum[mi][r];
      v += __shfl_xor(v, 1);
      v += __shfl_xor(v, 2);
      v += __shfl_xor(v, 4);
      v += __shfl_xor(v, 8);
      if (l15 == 0)
        rowRed[waveN][waveM * 64 + mi * 16 + quad * 4 + r] = v;
    }
  if (!diagBlk) {
    #pragma unroll
    for (int ni = 0; ni < 4; ni++) {
      float v = csum[ni];
      v += __shfl_xor(v, 16);
      v += __shfl_xor(v, 32);
      if (quad == 0)
        colRed[waveM][waveN * 64 + ni * 16 + l15] = v;
    }
  }
  __syncthreads();

  if (tid < BM) {
    atomicAdd(&sumexp[rowBase + tid], rowRed[0][tid] + rowRed[1][tid]);
  } else if (!diagBlk) {
    const int c = tid - BM;
    atomicAdd(&sumexp[colBase + c], colRed[0][c] + colRed[1][c]);
  }
}

// ---------------- Kernel 3: mean NLL --------------------------------------
__global__ __launch_bounds__(256) void finalize_kernel(
    const float* __restrict__ sumexp, const float* __restrict__ pos,
    float* __restrict__ out) {
  const int tid = threadIdx.x;
  const int row = blockIdx.x * 256 + tid;
  // pos holds d = logit*log2e for rows [0,4096); pos[i+4096] == pos[i]
  float local = -(pos[row & (N_ROWS / 2 - 1)] * LN2) + LOGIT_MAX + logf(sumexp[row]);
  #pragma unroll
  for (int off = 32; off > 0; off >>= 1) local += __shfl_xor(local, off);
  __shared__ float red[4];
  const int wave = tid >> 6, lane = tid & 63;
  if (lane == 0) red[wave] = local;
  __syncthreads();
  if (tid == 0)
    atomicAdd(out, (red[0] + red[1] + red[2] + red[3]) * (1.0f / N_ROWS));
}

extern "C" void kernel_launch(void* const* d_in, const int* in_sizes, int n_in,
                              void* d_out, int out_size, void* d_ws, size_t ws_size,
                              hipStream_t stream) {
  const float* z = (const float*)d_in[0];
  float* out = (float*)d_out;

  char* ws = (char*)d_ws;
  unsigned char* zn = (unsigned char*)ws;                    // 8 MB fp8
  float* sumexp = (float*)(ws + (size_t)N_ROWS * DIM);       // 32 KB
  float* pos    = sumexp + N_ROWS;                           // 16 KB

  normalize_kernel<<<N_ROWS / 4, 256, 0, stream>>>(z, zn, sumexp, out);
  fused_gemm_lse<<<NTILES, 256, 0, stream>>>(zn, sumexp, pos);
  finalize_kernel<<<N_ROWS / 256, 256, 0, stream>>>(sumexp, pos, out);
}

// Round 16
// 127.173 us; speedup vs baseline: 1.0077x; 1.0077x over previous
//
#include <hip/hip_runtime.h>
#include <hip/hip_bf16.h>
#include <hip/hip_fp8.h>

// ContrastiveLoss (SimCLR InfoNCE): N=8192, D=1024, T=0.1
// nll[i] = -logit[i, (i+N/2)%N] + logsumexp_j(logit[i,j]), diag masked out
// logit = cos_sim / T; out = mean(nll)
//
// Identities:
//  - q_i = round(127 * z_i/||z_i||) (int8; scale cancels, |q|<=127).
//    D = q_a . q_b (exact i32)  =>  d = D * (10*log2e)/127^2 = logit*log2e,
//    exp(logit-10) = 2^(d - 10*log2e) -> raw v_exp_f32. i8 quantization is
//    MORE accurate than fp8 e4m3 (7 vs 3 mantissa bits), which passed.
//  - logit in [-10,10] => FIXED-offset logsumexp; masked diag term == 0.
//  - Gram symmetric: upper-tri 128x128 supertiles (2080); off-diag tile
//    (I,J) adds exp row-sums to rows of I, col-sums to rows of J.
//  - positive-pair logits = tile diagonals of supertiles (I, I+32).
//
// R28: i8 K=64 MFMA -> BK=64 -> 34KB LDS -> 4 BLOCKS/CU. The MX-fp8 box is
// closed: reg budget 170 forbids more ILP (4 spill casualties R16/19/20/24),
// LDS forbids 4 blk at BK=128 (min 50KB) and 256^2 full-dbuf (>1 blk).
// mfma_i32_16x16x64_i8 (3944 TOPS = 85% of MX rate; MFMA not binding at
// 53us) halves BK: full A+B double-buffer = 2x8+2x8+2 = 34KB -> 4 blk at
// launch_bounds(256,4), and regs FIT: acc 64(int) + aa 16 + streamed bb 4
// + addr ~25 = ~110 < 128 (R24 spilled holding BOTH frag sets; B-dbuf
// legalizes streaming). Full dbuf deletes barrier2: ONE barrier/phase;
// stage(p+1) targets the other buffer (prior readers provably done: their
// ds_reads are consumed by MFMAs before barrier arrival); entry vmcnt(0)
// drains loads issued >=1 full phase ago (R25-proven ~free regime).
// Occupancy was the strongest lever (2->3 blk = -20%); 3->4 attacks the
// diagnosed DS/convoy wall with wave TLP. Supercell order, XOR swizzle
// (4-slot variant), epilogue algebra carried over; dequant (x DEQ) only in
// epilogue/pos. TRIPWIRES: WRITE ~18.6MB (spill), absmax clean.
// Predicted: gemm 52.9 -> 44-48us, Occupancy ~33%, MfmaUtil 29-33.
// Spill/race/regression => revert R27, declare practical floor.

#define N_ROWS 8192
#define DIM    1024
#define BM 128
#define BK 64                          // bytes (= elems) of K per phase
#define NPHASE (DIM / BK)              // 16
#define NT     (N_ROWS / BM)           // 64
#define NTILES (NT * (NT + 1) / 2)     // 2080
#define OFFS   14.4269504088896340f    // 10 * log2e
#define DEQ    8.9446659784243e-4f     // 10*log2e / 127^2
#define LN2    0.6931471805599453f
#define LOGIT_MAX 10.0f

typedef float floatx4 __attribute__((ext_vector_type(4)));
typedef int   intx4   __attribute__((ext_vector_type(4)));

__device__ __forceinline__ void async_copy16(const void* g, void* lds) {
  __builtin_amdgcn_global_load_lds(
      (const __attribute__((address_space(1))) void*)g,
      (__attribute__((address_space(3))) void*)lds, 16, 0, 0);
}

__device__ __forceinline__ unsigned pack4_i8(float a, float b, float c, float d) {
  const int qa = __float2int_rn(a), qb = __float2int_rn(b);
  const int qc = __float2int_rn(c), qd = __float2int_rn(d);
  return (qa & 0xFF) | ((qb & 0xFF) << 8) | ((qc & 0xFF) << 16)
       | ((qd & 0xFF) << 24);
}

// ---------------- Kernel 1: row normalize -> int8 (+ zero accumulators) ---
__global__ __launch_bounds__(256) void normalize_kernel(
    const float* __restrict__ z, unsigned char* __restrict__ zn,
    float* __restrict__ sumexp, float* __restrict__ out) {
  const int tid = threadIdx.x, wave = tid >> 6, lane = tid & 63;
  const int row = blockIdx.x * 4 + wave;

  if (blockIdx.x < 8) ((float4*)sumexp)[blockIdx.x * 256 + tid] = float4{0, 0, 0, 0};
  if (blockIdx.x == 8 && tid == 0) out[0] = 0.0f;

  const float4* zr = (const float4*)(z + (size_t)row * DIM);
  float4 v[4];
  #pragma unroll
  for (int j = 0; j < 4; j++) v[j] = zr[lane + 64 * j];
  float ss = 0.0f;
  #pragma unroll
  for (int j = 0; j < 4; j++)
    ss += v[j].x * v[j].x + v[j].y * v[j].y + v[j].z * v[j].z + v[j].w * v[j].w;
  #pragma unroll
  for (int off = 32; off > 0; off >>= 1) ss += __shfl_xor(ss, off);
  const float scale = rsqrtf(ss) * 127.0f;  // q = round(127 * z/||z||)

  unsigned* o = (unsigned*)(zn + (size_t)row * DIM);
  #pragma unroll
  for (int j = 0; j < 4; j++)
    o[lane + 64 * j] = pack4_i8(v[j].x * scale, v[j].y * scale,
                                v[j].z * scale, v[j].w * scale);
}

// Supercell-major tile decode: 64x64 upper-tri grid partitioned into 8x8
// supercells (rows SI, cols SJ >= SI). Diag cell = 36 tiles, off-diag = 64.
// Prefix P(SI) = 516*SI - 32*SI*SI (P(8)=2080). Within a cell-row: diag
// cell first, then snake over off-diag cells; within cell row-major.
// Confirmed R17: FETCH 66->23MB, gemm 65.3->56.4us.
__device__ __forceinline__ void decode_tile(int g, int& I, int& J) {
  int SI = 0;
  #pragma unroll
  for (int s = 1; s < 8; ++s)
    if (516 * s - 32 * s * s <= g) SI = s;
  int rem = g - (516 * SI - 32 * SI * SI);
  int i, j, SJ;
  if (rem < 36) {                       // diagonal supercell, upper-tri 8x8
    SJ = SI;
    i = 0;
    while ((i + 1) * (17 - (i + 1)) / 2 <= rem) ++i;  // prefix(i)=i*(17-i)/2
    j = i + (rem - i * (17 - i) / 2);
  } else {                              // full off-diagonal supercell
    const int rem2 = rem - 36;
    const int cc = rem2 >> 6;           // 0 .. (6-SI)
    const int k  = rem2 & 63;
    SJ = (SI & 1) ? (7 - cc) : (SI + 1 + cc);
    i = k >> 3;
    j = k & 7;
  }
  I = SI * 8 + i;
  J = SJ * 8 + j;
}

// ---------------- Kernel 2: upper-tri i8 GEMM + partial sum-exp -----------
__global__ __launch_bounds__(256, 4) void fused_gemm_lse(
    const unsigned char* __restrict__ zn, float* __restrict__ sumexp,
    float* __restrict__ pos) {
  __shared__ unsigned char sA[2][BM * BK];    // 2 x 8 KB (double buffer)
  __shared__ unsigned char sB[2][BM * BK];    // 2 x 8 KB (double buffer)
  __shared__ float rowRed[2][BM];             // 1 KB
  __shared__ float colRed[2][BM];             // 1 KB   (total 34 KB -> 4 blk)

  const int tid  = threadIdx.x;
  const int lane = tid & 63;
  const int wave = tid >> 6;
  const int quad = lane >> 4;
  const int l15  = lane & 15;
  const int waveM = wave >> 1;  // 0..1
  const int waveN = wave & 1;   // 0..1

  // XCD-contiguous tile permutation (2080 = 8 * 260)
  const int t = (blockIdx.x & 7) * (NTILES / 8) + (blockIdx.x >> 3);
  int I, J;
  decode_tile(t, I, J);
  const int rowBase = I * BM, colBase = J * BM;

  // staging: 128x64B tile = 512 16B-chunks, 2/thread/matrix.
  // chunk s = i*256+tid: row r = s>>2 (4 chunks/row), stored slot s&3 holds
  // logical k-chunk q = (s&3)^(r&3) (XOR swizzle on global-address side).
  // LDS dest is linear: s*16 = i*4096 + tid*16.
  int rOff[2];
  #pragma unroll
  for (int i = 0; i < 2; i++) {
    const int s = i * 256 + tid;
    const int r = s >> 2;
    const int q = (s & 3) ^ (r & 3);
    rOff[i] = r * DIM + q * 16;
  }
  const unsigned char* gA = zn + (size_t)rowBase * DIM;
  const unsigned char* gB = zn + (size_t)colBase * DIM;
  const int ldsOff = tid * 16;

  auto stage = [&](int buf, int p) {    // 4 DMA insts: 2 A + 2 B
    const unsigned char* ga = gA + p * BK;
    const unsigned char* gb = gB + p * BK;
    #pragma unroll
    for (int i = 0; i < 2; i++)
      async_copy16(ga + rOff[i], (char*)sA[buf] + i * 4096 + ldsOff);
    #pragma unroll
    for (int i = 0; i < 2; i++)
      async_copy16(gb + rOff[i], (char*)sB[buf] + i * 4096 + ldsOff);
  };

  intx4 acc[4][4];
  #pragma unroll
  for (int mi = 0; mi < 4; mi++)
    #pragma unroll
    for (int ni = 0; ni < 4; ni++) acc[mi][ni] = {0, 0, 0, 0};

  // frag-read constants: slot c = quad ^ (r&3); r&3 == l15&3 (bases mult 16)
  const int cA = quad ^ (l15 & 3);

  // prologue: phases 0,1 in flight (8 insts)
  stage(0, 0);
  stage(1, 1);

  for (int p = 0; p < NPHASE; ++p) {
    const int b = p & 1;
    // entry: phase p's 4 loads issued >= 1 full phase ago -> wait ~free.
    // p=0: keep phase-1's 4 flying (vmcnt(4)); p>=1: drain all (vmcnt(0)).
    if (p == 0) asm volatile("s_waitcnt vmcnt(4)" ::: "memory");
    else        asm volatile("s_waitcnt vmcnt(0)" ::: "memory");
    __builtin_amdgcn_s_barrier();       // buf[b] ready; all waves past p-1

    // stage p+1 into the OTHER buffer (p=0's is pre-staged). Safe: every
    // wave's phase-(p-1) reads of buf[b^1] were consumed by its MFMAs
    // before it arrived at this barrier.
    if (p >= 1 && p + 1 < NPHASE) stage(b ^ 1, p + 1);

    // hold A (4 x b128), stream B one fragment at a time
    intx4 aa[4];
    #pragma unroll
    for (int mi = 0; mi < 4; mi++) {
      const int r = waveM * 64 + mi * 16 + l15;
      aa[mi] = *(const intx4*)(&sA[b][(r * 4 + cA) * 16]);
    }
    __builtin_amdgcn_s_setprio(1);
    #pragma unroll
    for (int ni = 0; ni < 4; ni++) {
      const int r = waveN * 64 + ni * 16 + l15;
      const intx4 bb = *(const intx4*)(&sB[b][(r * 4 + cA) * 16]);
      #pragma unroll
      for (int mi = 0; mi < 4; mi++)
        acc[mi][ni] = __builtin_amdgcn_mfma_i32_16x16x64_i8(
            aa[mi], bb, acc[mi][ni], 0, 0, 0);
    }
    __builtin_amdgcn_s_setprio(0);
  }

  // ---- epilogue ----
  // C/D layout (16x16 shape family): col = lane&15, row = quad*4 + reg
  const bool diagBlk = (I == J);

  if (J == I + 32 && waveM == waveN) {  // positive-pair supertile
    #pragma unroll
    for (int mi = 0; mi < 4; mi++)
      #pragma unroll
      for (int r = 0; r < 4; r++)
        if (l15 == quad * 4 + r)
          pos[rowBase + waveM * 64 + mi * 16 + l15] = (float)acc[mi][mi][r] * DEQ;
  }

  float rsum[4][4], csum[4];
  #pragma unroll
  for (int mi = 0; mi < 4; mi++)
    #pragma unroll
    for (int r = 0; r < 4; r++) rsum[mi][r] = 0.0f;
  #pragma unroll
  for (int ni = 0; ni < 4; ni++) csum[ni] = 0.0f;

  if (diagBlk) {
    #pragma unroll
    for (int mi = 0; mi < 4; mi++)
      #pragma unroll
      for (int ni = 0; ni < 4; ni++) {
        const bool dtile = (waveM == waveN) && (mi == ni);
        #pragma unroll
        for (int r = 0; r < 4; r++) {
          float e = exp2f(fmaf((float)acc[mi][ni][r], DEQ, -OFFS));
          if (dtile && l15 == quad * 4 + r) e = 0.0f;  // masked diagonal
          rsum[mi][r] += e;
        }
      }
  } else {
    #pragma unroll
    for (int mi = 0; mi < 4; mi++)
      #pragma unroll
      for (int ni = 0; ni < 4; ni++)
        #pragma unroll
        for (int r = 0; r < 4; r++) {
          const float e = exp2f(fmaf((float)acc[mi][ni][r], DEQ, -OFFS));
          rsum[mi][r] += e;
          csum[ni]    += e;
        }
  }

  #pragma unroll
  for (int mi = 0; mi < 4; mi++)
    #pragma unroll
    for (int r = 0; r < 4; r++) {
      float v = rsum[mi][r];
      v += __shfl_xor(v, 1);
      v += __shfl_xor(v, 2);
      v += __shfl_xor(v, 4);
      v += __shfl_xor(v, 8);
      if (l15 == 0)
        rowRed[waveN][waveM * 64 + mi * 16 + quad * 4 + r] = v;
    }
  if (!diagBlk) {
    #pragma unroll
    for (int ni = 0; ni < 4; ni++) {
      float v = csum[ni];
      v += __shfl_xor(v, 16);
      v += __shfl_xor(v, 32);
      if (quad == 0)
        colRed[waveM][waveN * 64 + ni * 16 + l15] = v;
    }
  }
  __syncthreads();

  if (tid < BM) {
    atomicAdd(&sumexp[rowBase + tid], rowRed[0][tid] + rowRed[1][tid]);
  } else if (!diagBlk) {
    const int c = tid - BM;
    atomicAdd(&sumexp[colBase + c], colRed[0][c] + colRed[1][c]);
  }
}

// ---------------- Kernel 3: mean NLL --------------------------------------
__global__ __launch_bounds__(256) void finalize_kernel(
    const float* __restrict__ sumexp, const float* __restrict__ pos,
    float* __restrict__ out) {
  const int tid = threadIdx.x;
  const int row = blockIdx.x * 256 + tid;
  // pos holds d = logit*log2e for rows [0,4096); pos[i+4096] == pos[i]
  float local = -(pos[row & (N_ROWS / 2 - 1)] * LN2) + LOGIT_MAX + logf(sumexp[row]);
  #pragma unroll
  for (int off = 32; off > 0; off >>= 1) local += __shfl_xor(local, off);
  __shared__ float red[4];
  const int wave = tid >> 6, lane = tid & 63;
  if (lane == 0) red[wave] = local;
  __syncthreads();
  if (tid == 0)
    atomicAdd(out, (red[0] + red[1] + red[2] + red[3]) * (1.0f / N_ROWS));
}

extern "C" void kernel_launch(void* const* d_in, const int* in_sizes, int n_in,
                              void* d_out, int out_size, void* d_ws, size_t ws_size,
                              hipStream_t stream) {
  const float* z = (const float*)d_in[0];
  float* out = (float*)d_out;

  char* ws = (char*)d_ws;
  unsigned char* zn = (unsigned char*)ws;                    // 8 MB int8
  float* sumexp = (float*)(ws + (size_t)N_ROWS * DIM);       // 32 KB
  float* pos    = sumexp + N_ROWS;                           // 16 KB

  normalize_kernel<<<N_ROWS / 4, 256, 0, stream>>>(z, zn, sumexp, out);
  fused_gemm_lse<<<NTILES, 256, 0, stream>>>(zn, sumexp, pos);
  finalize_kernel<<<N_ROWS / 256, 256, 0, stream>>>(sumexp, pos, out);
}

// Round 17
// 125.841 us; speedup vs baseline: 1.0183x; 1.0106x over previous
//
#include <hip/hip_runtime.h>
#include <hip/hip_bf16.h>
#include <hip/hip_fp8.h>

// ContrastiveLoss (SimCLR InfoNCE): N=8192, D=1024, T=0.1
// nll[i] = -logit[i, (i+N/2)%N] + logsumexp_j(logit[i,j]), diag masked out
// logit = cos_sim / T; out = mean(nll)
//
// Identities:
//  - zn_i = z_i * sqrt(10*log2e)/||z_i||  =>  dot d = logit*log2e and
//    exp(logit-10) = 2^(d - 10*log2e) -> raw v_exp_f32.
//  - logit in [-10,10] => FIXED-offset logsumexp; masked diag term == 0.
//  - Gram symmetric: upper-tri 128x128 supertiles (2080); off-diag tile
//    (I,J) adds exp row-sums to rows of I, col-sums to rows of J.
//  - positive-pair logits = tile diagonals of supertiles (I, I+32).
//  - MX-scaled fp8 K=128 MFMA with all scales = 1.0 (2x bf16 rate).
//
// R29 = R27/R25 restored (verified best: gemm 52.8-54.0us, total 121.4us).
// R28 (i8 BK=64, 4 blk/CU, occupancy 34.5%, zero spill) REGRESSED to
// 63.6-66us -> occupancy/TLP is not the binding term; per-load flight time
// is. Session model fitting all 17 rounds: time = phases x (exposed-load-
// latency + serial pre-barrier chain), minimized jointly by (a) >=1 full
// phase of flight per staged load (counted vmcnt, R25 win / R12+R28 loss),
// (b) minimal phase count (BK=128), (c) reads-only pre-barrier chain (R26
// loss), (d) L2-hot bytes (R17 supercell win). This kernel sits at that
// minimum. Closed axes: occupancy (R28), tile 256^2 (R20/R22 spill or
// 1-blk), dtype/BK (R28), staging mechanism (R15/R19/R23), direct-global
// operands (R21), schedule depth (R13/14/18/26), 4-blk registers (R24).
// Phase: entry vmcnt(4)+barrier (B(p),A(p) issued >=1 phase ago -> ~free;
// newest 4 = A(p+2) stay flying; only p=7 drains) -> hoist both frag sets
// -> lgkm(0)+barrier2 -> stage B(p+1) + A(p+2) -> 16 MFMA under setprio.
// 50KB LDS, 3 blk/CU, VGPR 84 / WRITE 18.6MB clean. Practical floor for
// this structure on gfx950 (no pipe saturated; every legal reorganization
// inside the resource envelope tested and bested by this one).

#define N_ROWS 8192
#define DIM    1024
#define BM 128
#define BK 128                         // bytes (= elems) of K per phase
#define NPHASE (DIM / BK)              // 8
#define NT     (N_ROWS / BM)           // 64
#define NTILES (NT * (NT + 1) / 2)     // 2080
#define OFFS   14.4269504088896340f    // 10 * log2e
#define ROW_SCALE 3.7982825605f        // sqrt(10 * log2e)
#define LN2    0.6931471805599453f
#define LOGIT_MAX 10.0f
#define SCALE1 0x7F7F7F7F              // e8m0 1.0 in every byte

typedef float floatx4 __attribute__((ext_vector_type(4)));
typedef int   intx4   __attribute__((ext_vector_type(4)));
typedef int   intx8   __attribute__((ext_vector_type(8)));

__device__ __forceinline__ void async_copy16(const void* g, void* lds) {
  __builtin_amdgcn_global_load_lds(
      (const __attribute__((address_space(1))) void*)g,
      (__attribute__((address_space(3))) void*)lds, 16, 0, 0);
}

__device__ __forceinline__ unsigned pack4_e4m3(float a, float b, float c, float d) {
  __hip_fp8_e4m3 qa(a), qb(b), qc(c), qd(d);
  return (unsigned)qa.__x | ((unsigned)qb.__x << 8) |
         ((unsigned)qc.__x << 16) | ((unsigned)qd.__x << 24);
}

// ---------------- Kernel 1: row normalize -> fp8 (+ zero accumulators) ----
__global__ __launch_bounds__(256) void normalize_kernel(
    const float* __restrict__ z, unsigned char* __restrict__ zn,
    float* __restrict__ sumexp, float* __restrict__ out) {
  const int tid = threadIdx.x, wave = tid >> 6, lane = tid & 63;
  const int row = blockIdx.x * 4 + wave;

  if (blockIdx.x < 8) ((float4*)sumexp)[blockIdx.x * 256 + tid] = float4{0, 0, 0, 0};
  if (blockIdx.x == 8 && tid == 0) out[0] = 0.0f;

  const float4* zr = (const float4*)(z + (size_t)row * DIM);
  float4 v[4];
  #pragma unroll
  for (int j = 0; j < 4; j++) v[j] = zr[lane + 64 * j];
  float ss = 0.0f;
  #pragma unroll
  for (int j = 0; j < 4; j++)
    ss += v[j].x * v[j].x + v[j].y * v[j].y + v[j].z * v[j].z + v[j].w * v[j].w;
  #pragma unroll
  for (int off = 32; off > 0; off >>= 1) ss += __shfl_xor(ss, off);
  const float scale = rsqrtf(ss) * ROW_SCALE;  // norms ~32 >> eps

  unsigned* o = (unsigned*)(zn + (size_t)row * DIM);
  #pragma unroll
  for (int j = 0; j < 4; j++)
    o[lane + 64 * j] = pack4_e4m3(v[j].x * scale, v[j].y * scale,
                                  v[j].z * scale, v[j].w * scale);
}

// Supercell-major tile decode: 64x64 upper-tri grid partitioned into 8x8
// supercells (rows SI, cols SJ >= SI). Diag cell = 36 tiles, off-diag = 64.
// Prefix P(SI) = 516*SI - 32*SI*SI (P(8)=2080). Within a cell-row: diag
// cell first, then snake over off-diag cells; within cell row-major.
// Confirmed R17: FETCH 66->23MB, gemm 65.3->56.4us.
__device__ __forceinline__ void decode_tile(int g, int& I, int& J) {
  int SI = 0;
  #pragma unroll
  for (int s = 1; s < 8; ++s)
    if (516 * s - 32 * s * s <= g) SI = s;
  int rem = g - (516 * SI - 32 * SI * SI);
  int i, j, SJ;
  if (rem < 36) {                       // diagonal supercell, upper-tri 8x8
    SJ = SI;
    i = 0;
    while ((i + 1) * (17 - (i + 1)) / 2 <= rem) ++i;  // prefix(i)=i*(17-i)/2
    j = i + (rem - i * (17 - i) / 2);
  } else {                              // full off-diagonal supercell
    const int rem2 = rem - 36;
    const int cc = rem2 >> 6;           // 0 .. (6-SI)
    const int k  = rem2 & 63;
    SJ = (SI & 1) ? (7 - cc) : (SI + 1 + cc);
    i = k >> 3;
    j = k & 7;
  }
  I = SI * 8 + i;
  J = SJ * 8 + j;
}

// ---------------- Kernel 2: upper-tri MX-fp8 GEMM + partial sum-exp -------
__global__ __launch_bounds__(256, 3) void fused_gemm_lse(
    const unsigned char* __restrict__ zn, float* __restrict__ sumexp,
    float* __restrict__ pos) {
  __shared__ unsigned char sA[2][BM * BK];    // 2 x 16 KB (2-deep DMA dbuf)
  __shared__ unsigned char sB[BM * BK];       // 16 KB (single, 1-deep)
  __shared__ float rowRed[2][BM];             // 1 KB
  __shared__ float colRed[2][BM];             // 1 KB   (total 50 KB)

  const int tid  = threadIdx.x;
  const int lane = tid & 63;
  const int wave = tid >> 6;
  const int quad = lane >> 4;
  const int l15  = lane & 15;
  const int waveM = wave >> 1;  // 0..1
  const int waveN = wave & 1;   // 0..1

  // XCD-contiguous tile permutation (2080 = 8 * 260)
  const int t = (blockIdx.x & 7) * (NTILES / 8) + (blockIdx.x >> 3);
  int I, J;
  decode_tile(t, I, J);
  const int rowBase = I * BM, colBase = J * BM;

  // staging: 128x128B tile = 1024 16B-chunks, 4/thread/matrix.
  // chunk s = i*256+tid: row r = s>>3, stored slot s&7 holds logical
  // k-chunk q = (s&7)^(r&7) (XOR swizzle on the global-address side).
  // LDS dest is linear: s*16 = i*4096 + tid*16.
  int rOff[4];
  #pragma unroll
  for (int i = 0; i < 4; i++) {
    const int s = i * 256 + tid;
    const int r = s >> 3;
    const int q = (s & 7) ^ (r & 7);
    rOff[i] = r * DIM + q * 16;
  }
  const unsigned char* gA = zn + (size_t)rowBase * DIM;
  const unsigned char* gB = zn + (size_t)colBase * DIM;
  const int ldsOff = tid * 16;

  auto stageA = [&](int buf, int p) {
    const unsigned char* g = gA + p * BK;
    #pragma unroll
    for (int i = 0; i < 4; i++)
      async_copy16(g + rOff[i], (char*)sA[buf] + i * 4096 + ldsOff);
  };
  auto stageB = [&](int p) {
    const unsigned char* g = gB + p * BK;
    #pragma unroll
    for (int i = 0; i < 4; i++)
      async_copy16(g + rOff[i], (char*)sB + i * 4096 + ldsOff);
  };

  floatx4 acc[4][4];
  #pragma unroll
  for (int mi = 0; mi < 4; mi++)
    #pragma unroll
    for (int ni = 0; ni < 4; ni++) acc[mi][ni] = {0.f, 0.f, 0.f, 0.f};

  // prologue: B(0), A(0), A(1) in flight (12 insts); entry p=0 waits
  // vmcnt(4) -> drains B(0),A(0), leaves A(1) flying (steady invariant).
  stageB(0);
  stageA(0, 0);
  stageA(1, 1);

  for (int p = 0; p < NPHASE; ++p) {
    const int b = p & 1;
    // entry: B(p),A(p) resident (issued >= 1 full phase ago -> wait ~free);
    // newest 4 outstanding = A(p+2)'s predecessor set; only p=7 drains all.
    if (p < NPHASE - 1) asm volatile("s_waitcnt vmcnt(4)" ::: "memory");
    else                asm volatile("s_waitcnt vmcnt(0)" ::: "memory");
    __builtin_amdgcn_s_barrier();

    // hoist BOTH operand fragment sets (barrier2 then covers all reads)
    intx8 aa[4], bb[4];
    #pragma unroll
    for (int ni = 0; ni < 4; ni++) {
      const int r = waveN * 64 + ni * 16 + l15;
      const int c0 = (quad * 2) ^ (r & 7);
      const intx4 lo = *(const intx4*)(&sB[0] + (r * 8 + c0) * 16);
      const intx4 hi = *(const intx4*)(&sB[0] + (r * 8 + (c0 ^ 1)) * 16);
      bb[ni] = __builtin_shufflevector(lo, hi, 0, 1, 2, 3, 4, 5, 6, 7);
    }
    #pragma unroll
    for (int mi = 0; mi < 4; mi++) {
      const int r = waveM * 64 + mi * 16 + l15;
      const int c0 = (quad * 2) ^ (r & 7);
      const intx4 lo = *(const intx4*)(&sA[b][0] + (r * 8 + c0) * 16);
      const intx4 hi = *(const intx4*)(&sA[b][0] + (r * 8 + (c0 ^ 1)) * 16);
      aa[mi] = __builtin_shufflevector(lo, hi, 0, 1, 2, 3, 4, 5, 6, 7);
    }
    asm volatile("s_waitcnt lgkmcnt(0)" ::: "memory");
    __builtin_amdgcn_sched_barrier(0);
    __builtin_amdgcn_s_barrier();        // all waves done with sB and sA[b]

    // stage: B(p+1) -> sB (freed), A(p+2) -> sA[b] (freed). Issue order
    // B-then-A keeps the entry vmcnt(4) invariant (newest 4 = A batch).
    if (p + 1 < NPHASE) stageB(p + 1);
    if (p + 2 < NPHASE) stageA(b, p + 2);

    __builtin_amdgcn_s_setprio(1);
    #pragma unroll
    for (int mi = 0; mi < 4; mi++)
      #pragma unroll
      for (int ni = 0; ni < 4; ni++)
        acc[mi][ni] = __builtin_amdgcn_mfma_scale_f32_16x16x128_f8f6f4(
            aa[mi], bb[ni], acc[mi][ni],
            0 /*cbsz: A=e4m3*/, 0 /*blgp: B=e4m3*/,
            0, SCALE1,   // opsel_a, scale_a = 1.0
            0, SCALE1);  // opsel_b, scale_b = 1.0
    __builtin_amdgcn_s_setprio(0);
  }

  // ---- epilogue ----
  // C/D layout (16x16 shape family): col = lane&15, row = quad*4 + reg
  const bool diagBlk = (I == J);

  if (J == I + 32 && waveM == waveN) {  // positive-pair supertile
    #pragma unroll
    for (int mi = 0; mi < 4; mi++)
      #pragma unroll
      for (int r = 0; r < 4; r++)
        if (l15 == quad * 4 + r)
          pos[rowBase + waveM * 64 + mi * 16 + l15] = acc[mi][mi][r];
  }

  float rsum[4][4], csum[4];
  #pragma unroll
  for (int mi = 0; mi < 4; mi++)
    #pragma unroll
    for (int r = 0; r < 4; r++) rsum[mi][r] = 0.0f;
  #pragma unroll
  for (int ni = 0; ni < 4; ni++) csum[ni] = 0.0f;

  if (diagBlk) {
    #pragma unroll
    for (int mi = 0; mi < 4; mi++)
      #pragma unroll
      for (int ni = 0; ni < 4; ni++) {
        const bool dtile = (waveM == waveN) && (mi == ni);
        #pragma unroll
        for (int r = 0; r < 4; r++) {
          float e = exp2f(acc[mi][ni][r] - OFFS);
          if (dtile && l15 == quad * 4 + r) e = 0.0f;  // masked diagonal
          rsum[mi][r] += e;
        }
      }
  } else {
    #pragma unroll
    for (int mi = 0; mi < 4; mi++)
      #pragma unroll
      for (int ni = 0; ni < 4; ni++)
        #pragma unroll
        for (int r = 0; r < 4; r++) {
          const float e = exp2f(acc[mi][ni][r] - OFFS);
          rsum[mi][r] += e;
          csum[ni]    += e;
        }
  }

  #pragma unroll
  for (int mi = 0; mi < 4; mi++)
    #pragma unroll
    for (int r = 0; r < 4; r++) {
      float v = rsum[mi][r];
      v += __shfl_xor(v, 1);
      v += __shfl_xor(v, 2);
      v += __shfl_xor(v, 4);
      v += __shfl_xor(v, 8);
      if (l15 == 0)
        rowRed[waveN][waveM * 64 + mi * 16 + quad * 4 + r] = v;
    }
  if (!diagBlk) {
    #pragma unroll
    for (int ni = 0; ni < 4; ni++) {
      float v = csum[ni];
      v += __shfl_xor(v, 16);
      v += __shfl_xor(v, 32);
      if (quad == 0)
        colRed[waveM][waveN * 64 + ni * 16 + l15] = v;
    }
  }
  __syncthreads();

  if (tid < BM) {
    atomicAdd(&sumexp[rowBase + tid], rowRed[0][tid] + rowRed[1][tid]);
  } else if (!diagBlk) {
    const int c = tid - BM;
    atomicAdd(&sumexp[colBase + c], colRed[0][c] + colRed[1][c]);
  }
}

// ---------------- Kernel 3: mean NLL --------------------------------------
__global__ __launch_bounds__(256) void finalize_kernel(
    const float* __restrict__ sumexp, const float* __restrict__ pos,
    float* __restrict__ out) {
  const int tid = threadIdx.x;
  const int row = blockIdx.x * 256 + tid;
  // pos holds d = logit*log2e for rows [0,4096); pos[i+4096] == pos[i]
  float local = -(pos[row & (N_ROWS / 2 - 1)] * LN2) + LOGIT_MAX + logf(sumexp[row]);
  #pragma unroll
  for (int off = 32; off > 0; off >>= 1) local += __shfl_xor(local, off);
  __shared__ float red[4];
  const int wave = tid >> 6, lane = tid & 63;
  if (lane == 0) red[wave] = local;
  __syncthreads();
  if (tid == 0)
    atomicAdd(out, (red[0] + red[1] + red[2] + red[3]) * (1.0f / N_ROWS));
}

extern "C" void kernel_launch(void* const* d_in, const int* in_sizes, int n_in,
                              void* d_out, int out_size, void* d_ws, size_t ws_size,
                              hipStream_t stream) {
  const float* z = (const float*)d_in[0];
  float* out = (float*)d_out;

  char* ws = (char*)d_ws;
  unsigned char* zn = (unsigned char*)ws;                    // 8 MB fp8
  float* sumexp = (float*)(ws + (size_t)N_ROWS * DIM);       // 32 KB
  float* pos    = sumexp + N_ROWS;                           // 16 KB

  normalize_kernel<<<N_ROWS / 4, 256, 0, stream>>>(z, zn, sumexp, out);
  fused_gemm_lse<<<NTILES, 256, 0, stream>>>(zn, sumexp, pos);
  finalize_kernel<<<N_ROWS / 256, 256, 0, stream>>>(sumexp, pos, out);
}